// Round 1
// baseline (244.677 us; speedup 1.0000x reference)
//
#include <hip/hip_runtime.h>

// YOLO layer: (64, 3*85, 44, 44) -> (64, 3*44*44, 85)
// Elementwise sigmoid/exp + grid/anchor transform + channel-last transpose.
// Memory-bound (253 MB traffic); LDS-staged transpose for coalescing on both sides.

#define BSZ      64
#define NA       3
#define NC       80
#define GRID     44
#define SPATIAL  (GRID * GRID)       // 1936
#define CH       (5 + NC)            // 85
#define TILE     64
#define TILES_PER_BA ((SPATIAL + TILE - 1) / TILE)   // 31 (last tile has 16 valid)
#define LDS_STRIDE   (TILE + 1)      // 65: breaks bank aliasing on the write-phase reads
#define STRIDE_F 8.0f                // 352 / 44

__device__ __forceinline__ float sigf(float x) {
    return 1.0f / (1.0f + __expf(-x));
}

__global__ __launch_bounds__(256, 4)
void yolo_kernel(const float* __restrict__ in, float* __restrict__ out) {
    __shared__ float tile[CH * LDS_STRIDE];   // 85*65*4 = 22,100 B

    const int bid = blockIdx.x;
    const int t   = bid % TILES_PER_BA;
    const int ba  = bid / TILES_PER_BA;      // b*NA + a
    const int a   = ba % NA;

    const int s0    = t * TILE;
    const int valid = min(TILE, SPATIAL - s0);

    // ANCHORS * STRIDE cancels the /STRIDE in SCALED_ANCHORS: use raw anchors.
    const float aw = (a == 0) ? 10.0f : (a == 1) ? 16.0f : 33.0f;
    const float ah = (a == 0) ? 13.0f : (a == 1) ? 30.0f : 23.0f;

    const int tid  = threadIdx.x;
    const int lane = tid & 63;

    // ---- load phase: coalesced reads along spatial, math applied in-flight ----
    const float* inbase = in + (size_t)ba * CH * SPATIAL + s0;
    for (int c = tid >> 6; c < CH; c += 4) {        // c is wave-uniform each iter
        if (lane < valid) {
            float v = inbase[(size_t)c * SPATIAL + lane];
            if (c == 0) {
                int gx = (s0 + lane) % GRID;
                v = (sigf(v) + (float)gx) * STRIDE_F;
            } else if (c == 1) {
                int gy = (s0 + lane) / GRID;
                v = (sigf(v) + (float)gy) * STRIDE_F;
            } else if (c == 2) {
                v = __expf(v) * aw;
            } else if (c == 3) {
                v = __expf(v) * ah;
            } else {
                v = sigf(v);                         // conf + 80 classes
            }
            tile[c * LDS_STRIDE + lane] = v;
        }
    }
    __syncthreads();

    // ---- store phase: fully coalesced contiguous writes (valid*85 floats) ----
    const size_t obase = ((size_t)ba * SPATIAL + s0) * CH;
    const int total = valid * CH;
    for (int k = tid; k < total; k += 256) {
        int s = k / CH;            // const-divisor -> magic-mul
        int c = k - s * CH;
        out[obase + k] = tile[c * LDS_STRIDE + s];
    }
}

extern "C" void kernel_launch(void* const* d_in, const int* in_sizes, int n_in,
                              void* d_out, int out_size, void* d_ws, size_t ws_size,
                              hipStream_t stream) {
    const float* in = (const float*)d_in[0];
    float* out = (float*)d_out;
    const int grid = BSZ * NA * TILES_PER_BA;   // 5952 blocks
    yolo_kernel<<<grid, 256, 0, stream>>>(in, out);
}

// Round 2
// 223.305 us; speedup vs baseline: 1.0957x; 1.0957x over previous
//
#include <hip/hip_runtime.h>

// YOLO layer: (64, 3*85, 44, 44) -> (64, 3*44*44, 85), fp32.
// Memory-bound (253 MB traffic, ~40 us roofline @ 6.3 TB/s).
// R1 was latency-bound (2.1 TB/s, VALUBusy 26%): scalar rolled loads -> ~1
// outstanding 256B load/wave vs 900cyc HBM latency. Fix: 6-deep pipelined
// float4 loads (1 KB/wave/instr), LDS transposed [s][c] stride-89 (2-way max
// bank aliasing both phases), coalesced scalar stores.

#define BSZ      64
#define NA       3
#define NC       80
#define GRID     44
#define SPATIAL  (GRID * GRID)       // 1936
#define CH       (5 + NC)            // 85
#define TILE     64
#define TILES_PER_BA ((SPATIAL + TILE - 1) / TILE)   // 31 (last tile: 16 valid)
#define LDSS     89                  // [s][c] row stride; (25s+c)%32 spreads banks
#define NF       (CH * (TILE / 4))   // 1360 float4 loads per block
#define NITER    ((NF + 255) / 256)  // 6
#define STRIDE_F 8.0f                // 352 / 44; cancels /STRIDE in scaled anchors

__device__ __forceinline__ float sigf(float x) {
    return 1.0f / (1.0f + __expf(-x));
}

__global__ __launch_bounds__(256, 4)
void yolo_kernel(const float* __restrict__ in, float* __restrict__ out) {
    __shared__ float tile[TILE * LDSS];   // 64*89*4 = 22,784 B -> ~6 blocks/CU

    const int bid = blockIdx.x;
    const int t   = bid % TILES_PER_BA;
    const int ba  = bid / TILES_PER_BA;   // b*NA + a
    const int a   = ba % NA;

    const int s0    = t * TILE;
    const int valid = min(TILE, SPATIAL - s0);   // 64 or 16; always mult of 4

    const float aw = (a == 0) ? 10.0f : (a == 1) ? 16.0f : 33.0f;
    const float ah = (a == 0) ? 13.0f : (a == 1) ? 30.0f : 23.0f;

    const int tid = threadIdx.x;
    const float* inbase = in + (size_t)ba * CH * SPATIAL + s0;

    // ---- phase 1a: issue ALL global loads first (bytes in flight) ----
    float4 v[NITER];
    #pragma unroll
    for (int i = 0; i < NITER; ++i) {
        int f = tid + i * 256;            // f -> (channel c, spatial quad q)
        int c = f >> 4, q = f & 15;
        if (f < NF && q * 4 < valid)
            v[i] = *(const float4*)(inbase + (size_t)c * SPATIAL + q * 4);
    }

    // ---- phase 1b: transform + LDS transpose write ----
    #pragma unroll
    for (int i = 0; i < NITER; ++i) {
        int f = tid + i * 256;
        int c = f >> 4, q = f & 15;
        if (f >= NF || q * 4 >= valid) continue;
        float r[4] = {v[i].x, v[i].y, v[i].z, v[i].w};
        #pragma unroll
        for (int j = 0; j < 4; ++j) {
            int   sl = q * 4 + j;         // local spatial
            int   gs = s0 + sl;           // global spatial
            float x  = r[j];
            float o;
            if (c == 0)      o = (sigf(x) + (float)(gs % GRID)) * STRIDE_F;
            else if (c == 1) o = (sigf(x) + (float)(gs / GRID)) * STRIDE_F;
            else if (c == 2) o = __expf(x) * aw;
            else if (c == 3) o = __expf(x) * ah;
            else             o = sigf(x);  // conf + 80 classes
            tile[sl * LDSS + c] = o;
        }
    }
    __syncthreads();

    // ---- phase 2: coalesced contiguous stores (valid*85 floats/block) ----
    const size_t obase = ((size_t)ba * SPATIAL + s0) * CH;
    const int total = valid * CH;
    #pragma unroll 4
    for (int k = tid; k < total; k += 256) {
        int s = k / CH;                   // magic-mul
        int c = k - s * CH;
        out[obase + k] = tile[s * LDSS + c];
    }
}

extern "C" void kernel_launch(void* const* d_in, const int* in_sizes, int n_in,
                              void* d_out, int out_size, void* d_ws, size_t ws_size,
                              hipStream_t stream) {
    const float* in = (const float*)d_in[0];
    float* out = (float*)d_out;
    const int grid = BSZ * NA * TILES_PER_BA;   // 5952 blocks
    yolo_kernel<<<grid, 256, 0, stream>>>(in, out);
}